// Round 2
// baseline (20689.142 us; speedup 1.0000x reference)
//
#include <hip/hip_runtime.h>
#include <math.h>

#define EPS_Q 1e-8f
constexpr int BM = 128, BN = 128, BK = 8, PAD = 4;

// Fused quantized-linear:
//   kernel<1>:  V = quant_combine(X @ U)        (quantize epilogue fused)
//   kernel<2>:  out = V @ Z_w + bias
// fp32 vector SGEMM (no fp32 MFMA on CDNA4). 128x128 tile, BK=8,
// 256 threads, 8x8 micro-tile per thread (4+4 split 64 apart so LDS
// b128 reads are <=2-way bank-aliased, which is free on gfx950).
template<int EPI>
__global__ __launch_bounds__(256, 4)
void qlin_sgemm(const float* __restrict__ A, const float* __restrict__ B,
                float* __restrict__ C, int M, int N, int K,
                const float* __restrict__ g_lx, const float* __restrict__ g_lw,
                const float* __restrict__ g_dx, const float* __restrict__ g_cb,
                const float* __restrict__ g_rcb, const float* __restrict__ g_bias)
{
    __shared__ float As[2][BK][BM + PAD];   // k-major (transposed on store)
    __shared__ float Bs[2][BK][BN + PAD];
    __shared__ float s_cb[16], s_rcb[16], s_mid[15], s_rmid[15];

    const int tid = threadIdx.x;
    const int tx  = tid & 15;
    const int ty  = tid >> 4;
    const int bm  = blockIdx.y * BM;
    const int bn  = blockIdx.x * BN;

    // staging assignments
    const int arow = tid >> 1;          // 0..127
    const int akc  = (tid & 1) * 4;     // 0 or 4
    const int brow = tid >> 5;          // 0..7
    const int bcol = (tid & 31) * 4;    // 0..124

    const float* Aptr = A + (size_t)(bm + arow) * K + akc;
    const float* Bptr = B + (size_t)brow * N + bn + bcol;

    // prologue: stage tile 0 into buffer 0
    float4 aR = *reinterpret_cast<const float4*>(Aptr);
    float4 bR = *reinterpret_cast<const float4*>(Bptr);
    As[0][akc + 0][arow] = aR.x;
    As[0][akc + 1][arow] = aR.y;
    As[0][akc + 2][arow] = aR.z;
    As[0][akc + 3][arow] = aR.w;
    *reinterpret_cast<float4*>(&Bs[0][brow][bcol]) = bR;

    if (EPI == 1 && tid < 16) { s_cb[tid] = g_cb[tid]; s_rcb[tid] = g_rcb[tid]; }
    __syncthreads();
    if (EPI == 1 && tid < 15) {   // visible by epilogue via later loop syncs
        s_mid[tid]  = 0.5f * (s_cb[tid] + s_cb[tid + 1]);
        s_rmid[tid] = 0.5f * (s_rcb[tid] + s_rcb[tid + 1]);
    }

    float acc[8][8] = {{0.0f}};
    const int NK = K / BK;
    for (int kt = 0; kt < NK; ++kt) {
        const int cur = kt & 1;
        const bool pf = (kt + 1) < NK;
        if (pf) {   // prefetch next tile into registers (hides under compute)
            aR = *reinterpret_cast<const float4*>(Aptr + (size_t)(kt + 1) * BK);
            bR = *reinterpret_cast<const float4*>(Bptr + (size_t)(kt + 1) * BK * N);
        }
        #pragma unroll
        for (int kk = 0; kk < BK; ++kk) {
            const float4 a0 = *reinterpret_cast<const float4*>(&As[cur][kk][ty * 4]);
            const float4 a1 = *reinterpret_cast<const float4*>(&As[cur][kk][64 + ty * 4]);
            const float4 b0 = *reinterpret_cast<const float4*>(&Bs[cur][kk][tx * 4]);
            const float4 b1 = *reinterpret_cast<const float4*>(&Bs[cur][kk][64 + tx * 4]);
            const float av[8] = {a0.x, a0.y, a0.z, a0.w, a1.x, a1.y, a1.z, a1.w};
            const float bv[8] = {b0.x, b0.y, b0.z, b0.w, b1.x, b1.y, b1.z, b1.w};
            #pragma unroll
            for (int i = 0; i < 8; ++i) {
                #pragma unroll
                for (int j = 0; j < 8; ++j)
                    acc[i][j] = fmaf(av[i], bv[j], acc[i][j]);
            }
        }
        if (pf) {   // write prefetched tile to the other buffer (safe: last
                    // read of that buffer completed before previous sync)
            const int nxt = cur ^ 1;
            As[nxt][akc + 0][arow] = aR.x;
            As[nxt][akc + 1][arow] = aR.y;
            As[nxt][akc + 2][arow] = aR.z;
            As[nxt][akc + 3][arow] = aR.w;
            *reinterpret_cast<float4*>(&Bs[nxt][brow][bcol]) = bR;
        }
        __syncthreads();
    }

    if (EPI == 1) {
        // fused double-quantize epilogue:
        //   z  = nearest(p / safe(lx), cb);  r = p - z*lx
        //   q  = nearest(r / safe(dx), rcb)
        //   v  = z*(lx*lw) + q*(dx*lw)
        float lxv[8], lwv[8], dxv[8];
        #pragma unroll
        for (int j = 0; j < 8; ++j) {
            const int c = bn + (j >> 2) * 64 + tx * 4 + (j & 3);
            lxv[j] = g_lx[c]; lwv[j] = g_lw[c]; dxv[j] = g_dx[c];
        }
        #pragma unroll
        for (int i = 0; i < 8; ++i) {
            const int row = bm + (i >> 2) * 64 + ty * 4 + (i & 3);
            float o[8];
            #pragma unroll
            for (int j = 0; j < 8; ++j) {
                const float p   = acc[i][j];
                const float lx  = lxv[j];
                const float slx = (fabsf(lx) < EPS_Q) ? EPS_Q : lx;
                const float z   = p / slx;
                int i1 = 0;
                #pragma unroll
                for (int k = 0; k < 15; ++k) i1 += (s_mid[k] < z) ? 1 : 0;
                const float zq  = s_cb[i1];
                const float dx  = dxv[j];
                const float sdx = (fabsf(dx) < EPS_Q) ? EPS_Q : dx;
                const float zr  = (p - zq * lx) / sdx;
                int i2 = 0;
                #pragma unroll
                for (int k = 0; k < 15; ++k) i2 += (s_rmid[k] < zr) ? 1 : 0;
                const float qr  = s_rcb[i2];
                o[j] = zq * (lx * lwv[j]) + qr * (dx * lwv[j]);
            }
            const float4 o0 = {o[0], o[1], o[2], o[3]};
            const float4 o1 = {o[4], o[5], o[6], o[7]};
            *reinterpret_cast<float4*>(&C[(size_t)row * N + bn + tx * 4]) = o0;
            *reinterpret_cast<float4*>(&C[(size_t)row * N + bn + 64 + tx * 4]) = o1;
        }
    } else {
        float bv[8];
        #pragma unroll
        for (int j = 0; j < 8; ++j)
            bv[j] = g_bias[bn + (j >> 2) * 64 + tx * 4 + (j & 3)];
        #pragma unroll
        for (int i = 0; i < 8; ++i) {
            const int row = bm + (i >> 2) * 64 + ty * 4 + (i & 3);
            const float4 o0 = {acc[i][0] + bv[0], acc[i][1] + bv[1],
                               acc[i][2] + bv[2], acc[i][3] + bv[3]};
            const float4 o1 = {acc[i][4] + bv[4], acc[i][5] + bv[5],
                               acc[i][6] + bv[6], acc[i][7] + bv[7]};
            *reinterpret_cast<float4*>(&C[(size_t)row * N + bn + tx * 4]) = o0;
            *reinterpret_cast<float4*>(&C[(size_t)row * N + bn + 64 + tx * 4]) = o1;
        }
    }
}

extern "C" void kernel_launch(void* const* d_in, const int* in_sizes, int n_in,
                              void* d_out, int out_size, void* d_ws, size_t ws_size,
                              hipStream_t stream)
{
    const float* X    = (const float*)d_in[0];  // [M, DIN]
    const float* U    = (const float*)d_in[1];  // [DIN, R]
    const float* lx   = (const float*)d_in[2];  // [R]
    const float* lw   = (const float*)d_in[3];  // [R]
    const float* Zw   = (const float*)d_in[4];  // [R, DOUT]
    const float* cb   = (const float*)d_in[5];  // [16] sorted
    const float* dx   = (const float*)d_in[6];  // [R]
    const float* rcb  = (const float*)d_in[7];  // [16] sorted
    const float* bias = (const float*)d_in[8];  // [DOUT]
    float* out = (float*)d_out;
    float* V   = (float*)d_ws;                  // [M, R] fp32 scratch (32 MB)

    const int R    = in_sizes[2];
    const int DIN  = in_sizes[1] / R;
    const int M    = in_sizes[0] / DIN;
    const int DOUT = in_sizes[8];

    // GEMM1 + fused quantize: V = quant(X @ U)
    qlin_sgemm<1><<<dim3(R / BN, M / BM), dim3(256), 0, stream>>>(
        X, U, V, M, R, DIN, lx, lw, dx, cb, rcb, nullptr);
    // GEMM2 + bias: out = V @ Z_w + bias
    qlin_sgemm<2><<<dim3(DOUT / BN, M / BM), dim3(256), 0, stream>>>(
        V, Zw, out, M, DOUT, R, nullptr, nullptr, nullptr, nullptr, nullptr, bias);
}

// Round 6
// 782.483 us; speedup vs baseline: 26.4404x; 26.4404x over previous
//
#include <hip/hip_runtime.h>
#include <math.h>

// R2 measured: fp32 SGEMM w/ spill bug = 20.7ms, epilogue numerics VALIDATED
// (absmax 0.03125 pass). R6: split-bf16 MFMA emulation (a*b ~= ah*bh + ah*bl
// + al*bh, 3x bf16 MFMA @ ~2.4PF >> 157TF fp32 VALU). hi/lo split done once
// at staging. 128x128 block, BK=32, 4 waves x (4x4) 16x16x32 frags.
// C/D layout (HW-verified): col=lane&15, row=(lane>>4)*4+reg.

typedef __bf16 bf16;
typedef bf16 bf16x2 __attribute__((ext_vector_type(2)));
typedef bf16 bf16x4 __attribute__((ext_vector_type(4)));
typedef bf16 bf16x8 __attribute__((ext_vector_type(8)));
typedef float f32x4 __attribute__((ext_vector_type(4)));

#define EPS_Q 1e-8f

constexpr int BM = 128, BN = 128, BK = 32;
constexpr int LDK = BK + 8;   // 40 bf16 = 80B row stride -> 2-way banks (free)

template<int EPI>
__global__ __launch_bounds__(256)
void qlin_mfma(const float* __restrict__ A, const float* __restrict__ B,
               float* __restrict__ C, int M, int N, int K,
               const float* __restrict__ g_lx, const float* __restrict__ g_lw,
               const float* __restrict__ g_dx, const float* __restrict__ g_cb,
               const float* __restrict__ g_rcb, const float* __restrict__ g_bias)
{
    __shared__ bf16 Ah[BM][LDK], Al[BM][LDK], Bh[BN][LDK], Bl[BN][LDK];
    __shared__ float s_cb[16], s_rcb[16], s_mid[15], s_rmid[15];

    const int tid = threadIdx.x;
    const int bm  = blockIdx.y * BM;
    const int bn  = blockIdx.x * BN;

    if (EPI == 1) {
        if (tid < 16) { s_cb[tid] = g_cb[tid]; s_rcb[tid] = g_rcb[tid]; }
        __syncthreads();
        if (tid < 15) {   // visible to epilogue via loop barriers
            s_mid[tid]  = 0.5f * (s_cb[tid] + s_cb[tid + 1]);
            s_rmid[tid] = 0.5f * (s_rcb[tid] + s_rcb[tid + 1]);
        }
    }

    // ---- staging assignment ----
    // A-tile [BM=128][BK=32]: thread -> 1 row, 16 consecutive k (4 float4)
    const int am  = tid >> 1;          // 0..127
    const int ak0 = (tid & 1) * 16;    // 0 / 16
    // B-tile [BK=32][BN=128]: thread -> 2 k-rows x 8 consecutive n
    const int bk  = (tid >> 4) * 2;    // 0,2,...,30
    const int bn0 = (tid & 15) * 8;    // 0..120

    const float* Abase = A + (size_t)(bm + am) * K + ak0;

    f32x4 rA[4], rB[4];

    auto LOADREGS = [&](int kt) {
        const float* ap = Abase + (size_t)kt * BK;
        #pragma unroll
        for (int q = 0; q < 4; ++q)
            rA[q] = *reinterpret_cast<const f32x4*>(ap + q * 4);
        #pragma unroll
        for (int q = 0; q < 4; ++q) {   // rB[q]: row q>>1, col chunk (q&1)*4
            rB[q] = *reinterpret_cast<const f32x4*>(
                B + (size_t)(kt * BK + bk + (q >> 1)) * N + bn + bn0 + (q & 1) * 4);
        }
    };

    auto WRITELDS = [&]() {
        #pragma unroll
        for (int q = 0; q < 4; ++q) {
            bf16x4 h, l;
            #pragma unroll
            for (int e = 0; e < 4; ++e) {
                const float x = rA[q][e];
                const bf16  hh = (bf16)x;
                h[e] = hh;
                l[e] = (bf16)(x - (float)hh);
            }
            *reinterpret_cast<bf16x4*>(&Ah[am][ak0 + q * 4]) = h;
            *reinterpret_cast<bf16x4*>(&Al[am][ak0 + q * 4]) = l;
        }
        const int js = tid & 7;          // swizzle write order -> 2-way banks
        #pragma unroll
        for (int jj = 0; jj < 8; ++jj) {
            const int j = (jj + js) & 7;
            const float x0 = rB[(j >> 2)][j & 3];        // k-row bk
            const float x1 = rB[2 + (j >> 2)][j & 3];    // k-row bk+1
            const bf16 h0 = (bf16)x0, h1 = (bf16)x1;
            const bf16 l0 = (bf16)(x0 - (float)h0), l1 = (bf16)(x1 - (float)h1);
            bf16x2 ph = {h0, h1}, pl = {l0, l1};
            *reinterpret_cast<bf16x2*>(&Bh[bn0 + j][bk]) = ph;   // transposed [n][k]
            *reinterpret_cast<bf16x2*>(&Bl[bn0 + j][bk]) = pl;
        }
    };

    // ---- wave / fragment decomposition ----
    const int ln  = tid & 63;
    const int wid = tid >> 6;
    const int wm  = (wid >> 1) * 64;   // wave row offset in block
    const int wn  = (wid & 1) * 64;    // wave col offset
    const int fr  = ln & 15;           // A row / B col within frag
    const int k8  = (ln >> 4) * 8;     // k-chunk of this lane

    f32x4 acc[4][4] = {};

    const int NK = K / BK;
    LOADREGS(0);
    for (int kt = 0; kt < NK; ++kt) {
        __syncthreads();               // prior compute finished reading LDS
        WRITELDS();
        __syncthreads();
        if (kt + 1 < NK) LOADREGS(kt + 1);   // global loads fly under compute

        bf16x8 fAh[4], fAl[4], fBh[4], fBl[4];
        #pragma unroll
        for (int mi = 0; mi < 4; ++mi) {
            fAh[mi] = *reinterpret_cast<const bf16x8*>(&Ah[wm + mi * 16 + fr][k8]);
            fAl[mi] = *reinterpret_cast<const bf16x8*>(&Al[wm + mi * 16 + fr][k8]);
        }
        #pragma unroll
        for (int nj = 0; nj < 4; ++nj) {
            fBh[nj] = *reinterpret_cast<const bf16x8*>(&Bh[wn + nj * 16 + fr][k8]);
            fBl[nj] = *reinterpret_cast<const bf16x8*>(&Bl[wn + nj * 16 + fr][k8]);
        }
        #pragma unroll
        for (int mi = 0; mi < 4; ++mi)
            #pragma unroll
            for (int nj = 0; nj < 4; ++nj) {
                acc[mi][nj] = __builtin_amdgcn_mfma_f32_16x16x32_bf16(
                    fAh[mi], fBh[nj], acc[mi][nj], 0, 0, 0);
                acc[mi][nj] = __builtin_amdgcn_mfma_f32_16x16x32_bf16(
                    fAh[mi], fBl[nj], acc[mi][nj], 0, 0, 0);
                acc[mi][nj] = __builtin_amdgcn_mfma_f32_16x16x32_bf16(
                    fAl[mi], fBh[nj], acc[mi][nj], 0, 0, 0);
            }
    }

    // ---- epilogue ----
    const int rbase = bm + wm + (ln >> 4) * 4;
    if (EPI == 1) {
        // hoist midpoints to regs (static index only; codebook value gathers
        // stay in LDS -- runtime-indexed reg arrays would go to scratch)
        float mid[15], rmid[15];
        #pragma unroll
        for (int k = 0; k < 15; ++k) { mid[k] = s_mid[k]; rmid[k] = s_rmid[k]; }
        #pragma unroll
        for (int nj = 0; nj < 4; ++nj) {
            const int c = bn + wn + nj * 16 + fr;
            const float lx = g_lx[c], lw = g_lw[c], dx = g_dx[c];
            const float slx = (fabsf(lx) < EPS_Q) ? EPS_Q : lx;
            const float sdx = (fabsf(dx) < EPS_Q) ? EPS_Q : dx;
            const float ilx = 1.0f / slx, isdx = 1.0f / sdx;
            const float c1 = lx * lw, c2 = dx * lw;
            #pragma unroll
            for (int mi = 0; mi < 4; ++mi)
                #pragma unroll
                for (int r = 0; r < 4; ++r) {
                    const float p = acc[mi][nj][r];
                    const float z = p * ilx;
                    int i1 = 0;
                    #pragma unroll
                    for (int k = 0; k < 15; ++k) i1 += (mid[k] < z) ? 1 : 0;
                    const float zq = s_cb[i1];
                    const float zr = (p - zq * lx) * isdx;
                    int i2 = 0;
                    #pragma unroll
                    for (int k = 0; k < 15; ++k) i2 += (rmid[k] < zr) ? 1 : 0;
                    const float qr = s_rcb[i2];
                    C[(size_t)(rbase + mi * 16 + r) * N + c] = zq * c1 + qr * c2;
                }
        }
    } else {
        #pragma unroll
        for (int nj = 0; nj < 4; ++nj) {
            const int c = bn + wn + nj * 16 + fr;
            const float bv = g_bias[c];
            #pragma unroll
            for (int mi = 0; mi < 4; ++mi)
                #pragma unroll
                for (int r = 0; r < 4; ++r)
                    C[(size_t)(rbase + mi * 16 + r) * N + c] = acc[mi][nj][r] + bv;
        }
    }
}

extern "C" void kernel_launch(void* const* d_in, const int* in_sizes, int n_in,
                              void* d_out, int out_size, void* d_ws, size_t ws_size,
                              hipStream_t stream)
{
    const float* X    = (const float*)d_in[0];  // [M, DIN]
    const float* U    = (const float*)d_in[1];  // [DIN, R]
    const float* lx   = (const float*)d_in[2];  // [R]
    const float* lw   = (const float*)d_in[3];  // [R]
    const float* Zw   = (const float*)d_in[4];  // [R, DOUT]
    const float* cb   = (const float*)d_in[5];  // [16] sorted
    const float* dx   = (const float*)d_in[6];  // [R]
    const float* rcb  = (const float*)d_in[7];  // [16] sorted
    const float* bias = (const float*)d_in[8];  // [DOUT]
    float* out = (float*)d_out;
    float* V   = (float*)d_ws;                  // [M, R] fp32 scratch (32 MB)

    const int R    = in_sizes[2];
    const int DIN  = in_sizes[1] / R;
    const int M    = in_sizes[0] / DIN;
    const int DOUT = in_sizes[8];

    // GEMM1 + fused double-quantize: V = quant(X @ U)
    qlin_mfma<1><<<dim3(R / BN, M / BM), dim3(256), 0, stream>>>(
        X, U, V, M, R, DIN, lx, lw, dx, cb, rcb, nullptr);
    // GEMM2 + bias: out = V @ Z_w + bias
    qlin_mfma<2><<<dim3(DOUT / BN, M / BM), dim3(256), 0, stream>>>(
        V, Zw, out, M, DOUT, R, nullptr, nullptr, nullptr, nullptr, nullptr, bias);
}